// Round 5
// baseline (268.113 us; speedup 1.0000x reference)
//
#include <hip/hip_runtime.h>
#include <cstddef>

#define WIN 11
#define HALO 10
#define NCH 10

typedef float v4f __attribute__((ext_vector_type(4)));

// Normalized 1D Gaussian, sigma=1.5 (constexpr: unrolled taps fold to immediates)
constexpr float Gc[WIN] = {
    0.00102838f, 0.00759876f, 0.03600077f, 0.10936069f, 0.21300554f,
    0.26601173f, 0.21300554f, 0.10936069f, 0.03600077f, 0.00759876f,
    0.00102838f};

struct Ptrs {
    const float* p[5];
    const float* t[5];
};

// ---- One-shot pyramid: 64x64 lvl0 tile -> lvl1..4, plus acc zeroing ----
// (~110 MB in ~15us ~= 7 TB/s: at the HBM/L3 roofline — do not touch)
__global__ __launch_bounds__(256) void pool_all(
    const float* __restrict__ P0, const float* __restrict__ T0,
    float* __restrict__ p1, float* __restrict__ t1,
    float* __restrict__ p2, float* __restrict__ t2,
    float* __restrict__ p3, float* __restrict__ t3,
    float* __restrict__ p4, float* __restrict__ t4,
    float* __restrict__ acc) {
    __shared__ float sp2[256], st2[256], sp3[64], st3[64];
    const int tid = threadIdx.x;
    if (blockIdx.x == 0 && tid < 128) acc[tid] = 0.f;

    const int b = blockIdx.x;  // 2560 = 10ch x 16 x 16
    const int bx = b & 15, by = (b >> 4) & 15, ch = b >> 8;
    const int tx = tid & 15, ty = tid >> 4;

    const size_t rbase =
        ((size_t)ch * 1024 + by * 64 + ty * 4) * 1024 + bx * 64 + tx * 4;
    float4 pr[4], tr[4];
#pragma unroll
    for (int r2 = 0; r2 < 4; ++r2) {
        pr[r2] = *(const float4*)(P0 + rbase + (size_t)r2 * 1024);
        tr[r2] = *(const float4*)(T0 + rbase + (size_t)r2 * 1024);
    }
    float p1a = 0.25f * ((pr[0].x + pr[0].y) + (pr[1].x + pr[1].y));
    float p1b = 0.25f * ((pr[0].z + pr[0].w) + (pr[1].z + pr[1].w));
    float p1c = 0.25f * ((pr[2].x + pr[2].y) + (pr[3].x + pr[3].y));
    float p1d = 0.25f * ((pr[2].z + pr[2].w) + (pr[3].z + pr[3].w));
    float t1a = 0.25f * ((tr[0].x + tr[0].y) + (tr[1].x + tr[1].y));
    float t1b = 0.25f * ((tr[0].z + tr[0].w) + (tr[1].z + tr[1].w));
    float t1c = 0.25f * ((tr[2].x + tr[2].y) + (tr[3].x + tr[3].y));
    float t1d = 0.25f * ((tr[2].z + tr[2].w) + (tr[3].z + tr[3].w));
    size_t o1 = ((size_t)ch * 512 + by * 32 + ty * 2) * 512 + bx * 32 + tx * 2;
    *(float2*)(p1 + o1) = make_float2(p1a, p1b);
    *(float2*)(p1 + o1 + 512) = make_float2(p1c, p1d);
    *(float2*)(t1 + o1) = make_float2(t1a, t1b);
    *(float2*)(t1 + o1 + 512) = make_float2(t1c, t1d);
    float p2v = 0.25f * ((p1a + p1b) + (p1c + p1d));
    float t2v = 0.25f * ((t1a + t1b) + (t1c + t1d));
    size_t o2 = ((size_t)ch * 256 + by * 16 + ty) * 256 + bx * 16 + tx;
    p2[o2] = p2v;
    t2[o2] = t2v;
    sp2[tid] = p2v;
    st2[tid] = t2v;
    __syncthreads();
    if (tid < 64) {
        int x3 = tid & 7, y3 = tid >> 3;
        int i0 = (2 * y3) * 16 + 2 * x3;
        float p3v = 0.25f * ((sp2[i0] + sp2[i0 + 1]) + (sp2[i0 + 16] + sp2[i0 + 17]));
        float t3v = 0.25f * ((st2[i0] + st2[i0 + 1]) + (st2[i0 + 16] + st2[i0 + 17]));
        size_t o3 = ((size_t)ch * 128 + by * 8 + y3) * 128 + bx * 8 + x3;
        p3[o3] = p3v;
        t3[o3] = t3v;
        sp3[tid] = p3v;
        st3[tid] = t3v;
    }
    __syncthreads();
    if (tid < 16) {
        int x4 = tid & 3, y4 = tid >> 2;
        int i0 = (2 * y4) * 8 + 2 * x4;
        float p4v = 0.25f * ((sp3[i0] + sp3[i0 + 1]) + (sp3[i0 + 8] + sp3[i0 + 9]));
        float t4v = 0.25f * ((st3[i0] + st3[i0 + 1]) + (st3[i0 + 8] + st3[i0 + 9]));
        size_t o4 = ((size_t)ch * 64 + by * 4 + y4) * 64 + bx * 4 + x4;
        p4[o4] = p4v;
        t4[o4] = t4v;
    }
}

// ---------------------------------------------------------------------------
// Wave-autonomous sliding-window SSIM. One wave = one 54-col x <=64-row output
// tile; lane = one output column. Per input row: load 2 px, build 4-channel
// xq, ds_write_b128 to a wave-private 2-row buffer, 11x ds_read_b128 for the
// h-conv, feed 11 statically-indexed v4f row-accumulators (rows unrolled in
// groups of 11 so every index is compile-time -> registers, never scratch).
// ZERO __syncthreads: waves stall only on their own counters; latency hidden
// by ~4 independent waves/SIMD (4110 uniform tasks / 1024 SIMDs). Global
// loads double-group pipelined (22 rows in flight, issued one group early).
// Intra-wave LDS RAW (write -> cross-lane read) guarded by sched_barrier(0x7F)
// (blocks DS reordering only) + the in-order per-wave DS pipe.
// Tasks/level (ncs x nrs x 10ch): L0 19x16, L1 10x8, L2 5x4, L3 3x2, L4 1x1.
// ---------------------------------------------------------------------------
constexpr int COLS = 54;
constexpr int SRMAX = 64;
constexpr int NTASK = 4110;

#define LOADG(PX, TX, RB)                       \
    {                                           \
        _Pragma("unroll")                       \
        for (int j_ = 0; j_ < 11; ++j_) {       \
            int rr_ = (RB) + j_;                \
            if (rr_ > nrowm1) rr_ = nrowm1;     \
            PX[j_] = Pb[rr_ * H];               \
            TX[j_] = Tb[rr_ * H];               \
        }                                       \
    }

#define EMIT(MC)                                                          \
    {                                                                     \
        v4f av_ = accv[MC];                                               \
        accv[MC] = (v4f){0.f, 0.f, 0.f, 0.f};                             \
        if (outok) {                                                      \
            float mu1 = av_.x, mu2 = av_.y;                               \
            float mu1s = mu1 * mu1, mu2s = mu2 * mu2, mu12 = mu1 * mu2;   \
            float v2 = av_.z - mu1s - mu2s + C2c;                         \
            float v1 = 2.f * (av_.w - mu12) + C2c;                        \
            float den2 = mu1s + mu2s + C1c;                               \
            float num2 = 2.f * mu12 + C1c;                                \
            float inv = __builtin_amdgcn_rcpf(v2 * den2);                 \
            cs_sum = fmaf(v1 * den2, inv, cs_sum);                        \
            sim_sum = fmaf(num2 * v1, inv, sim_sum);                      \
        }                                                                 \
    }

// Steady-state phase: row r = RB+PHI (r mod 11 == PHI since RB advances by
// 11/22). acc[m] holds output row o == m (mod 11), tap coeff Gc[(PHI-m)%11];
// acc[(PHI+1)%11] completes (o = r-10).
#define STEADY(PX, TX, RB, PHI)                                           \
    if ((RB) + (PHI) < nrow) {                                            \
        float pv_ = PX[PHI], tv_ = TX[PHI];                               \
        v4f xq_ = (v4f){pv_, tv_, pv_ * pv_ + tv_ * tv_, pv_ * tv_};      \
        v4f* b_ = lbase + ((((RB) + (PHI)) & 1) ? 80 : 0);                \
        b_[lane] = xq_;                                                   \
        __builtin_amdgcn_sched_barrier(0x7F);                             \
        v4f h_ = Gc[0] * b_[lane];                                        \
        _Pragma("unroll")                                                 \
        for (int k_ = 1; k_ < 11; ++k_) h_ += Gc[k_] * b_[lane + k_];     \
        _Pragma("unroll")                                                 \
        for (int m_ = 0; m_ < 11; ++m_)                                   \
            accv[m_] += Gc[((PHI) - m_ + 11) % 11] * h_;                  \
        EMIT(((PHI) + 1) % 11);                                           \
    }

// Prologue phase (rows 0..10): only outputs o=0..PHI exist yet; o=0 completes
// at PHI==10. nrow >= 64 so no row guard needed.
#define PRO(PX, TX, PHI)                                                  \
    {                                                                     \
        float pv_ = PX[PHI], tv_ = TX[PHI];                               \
        v4f xq_ = (v4f){pv_, tv_, pv_ * pv_ + tv_ * tv_, pv_ * tv_};      \
        v4f* b_ = lbase + (((PHI) & 1) ? 80 : 0);                         \
        b_[lane] = xq_;                                                   \
        __builtin_amdgcn_sched_barrier(0x7F);                             \
        v4f h_ = Gc[0] * b_[lane];                                        \
        _Pragma("unroll")                                                 \
        for (int k_ = 1; k_ < 11; ++k_) h_ += Gc[k_] * b_[lane + k_];     \
        _Pragma("unroll")                                                 \
        for (int m_ = 0; m_ <= (PHI); ++m_)                               \
            accv[m_] += Gc[(PHI) - m_] * h_;                              \
        if ((PHI) == 10) EMIT(0);                                         \
    }

#define GROUP(PX, TX, RB)      \
    STEADY(PX, TX, RB, 0)      \
    STEADY(PX, TX, RB, 1)      \
    STEADY(PX, TX, RB, 2)      \
    STEADY(PX, TX, RB, 3)      \
    STEADY(PX, TX, RB, 4)      \
    STEADY(PX, TX, RB, 5)      \
    STEADY(PX, TX, RB, 6)      \
    STEADY(PX, TX, RB, 7)      \
    STEADY(PX, TX, RB, 8)      \
    STEADY(PX, TX, RB, 9)      \
    STEADY(PX, TX, RB, 10)

__global__ __launch_bounds__(256, 4) void ssim_sw(Ptrs ptrs,
                                                  float* __restrict__ acc) {
    __shared__ v4f hq[4 * 160];  // per wave: 2 bufs x 80 slots (64 + zero pad)
    const int wid = threadIdx.x >> 6;
    const int lane = threadIdx.x & 63;
    const int task = blockIdx.x * 4 + wid;
    if (task >= NTASK) return;  // wave-uniform; no barriers in this kernel

    int lvl, ch, cs, rs;
    {
        int t;
        if (task < 3040)      { lvl = 0; t = task;        ch = t / 304; t -= ch * 304; rs = t / 19; cs = t - rs * 19; }
        else if (task < 3840) { lvl = 1; t = task - 3040; ch = t / 80;  t -= ch * 80;  rs = t / 10; cs = t - rs * 10; }
        else if (task < 4040) { lvl = 2; t = task - 3840; ch = t / 20;  t -= ch * 20;  rs = t / 5;  cs = t - rs * 5;  }
        else if (task < 4100) { lvl = 3; t = task - 4040; ch = t / 6;   t -= ch * 6;   rs = t / 3;  cs = t - rs * 3;  }
        else                  { lvl = 4; ch = task - 4100; rs = 0; cs = 0; }
    }
    const int H = 1024 >> lvl;
    const int Wout = H - HALO;
    const int X0 = cs * COLS;
    const int Y0 = rs * SRMAX;
    const int SR = (Wout - Y0 < SRMAX) ? (Wout - Y0) : SRMAX;
    const int nrow = SR + HALO;  // input rows this strip (74 or 64)
    const int nrowm1 = nrow - 1;

    const float* Pc = ptrs.p[lvl] + (size_t)ch * H * H;
    const float* Tc = ptrs.t[lvl] + (size_t)ch * H * H;
    // Clamped input column: always in-image; clamped lanes can never feed a
    // valid output (valid col x reads cols x..x+10 <= H-1 only).
    int gc = X0 + lane;
    if (gc > H - 1) gc = H - 1;
    const float* Pb = Pc + (size_t)Y0 * H + gc;
    const float* Tb = Tc + (size_t)Y0 * H + gc;
    const bool outok = (lane < COLS) && (X0 + lane < Wout);

    v4f* lbase = hq + wid * 160;
    if (lane < 16) {  // zero the read-overreach pads (slots 64..79 both bufs)
        lbase[64 + lane] = (v4f){0.f, 0.f, 0.f, 0.f};
        lbase[144 + lane] = (v4f){0.f, 0.f, 0.f, 0.f};
    }

    v4f accv[11];
#pragma unroll
    for (int m = 0; m < 11; ++m) accv[m] = (v4f){0.f, 0.f, 0.f, 0.f};
    float cs_sum = 0.f, sim_sum = 0.f;
    const float C1c = 1.0e-4f, C2c = 9.0e-4f;

    float pA[11], tA[11], pB[11], tB[11];
    LOADG(pA, tA, 0);
    LOADG(pB, tB, 11);

    PRO(pA, tA, 0)
    PRO(pA, tA, 1)
    PRO(pA, tA, 2)
    PRO(pA, tA, 3)
    PRO(pA, tA, 4)
    PRO(pA, tA, 5)
    PRO(pA, tA, 6)
    PRO(pA, tA, 7)
    PRO(pA, tA, 8)
    PRO(pA, tA, 9)
    PRO(pA, tA, 10)

    int rb = 11;
    for (;;) {
        LOADG(pA, tA, rb + 11);   // prefetch next group (clamped at tail)
        GROUP(pB, tB, rb);        // rows rb..rb+10
        if (rb + 11 >= nrow) break;
        LOADG(pB, tB, rb + 22);
        GROUP(pA, tA, rb + 11);   // rows rb+11..rb+21
        if (rb + 22 >= nrow) break;
        rb += 22;
    }

    // ---- Wave reduction + one atomic pair per wave ----
#pragma unroll
    for (int off = 32; off > 0; off >>= 1) {
        cs_sum += __shfl_down(cs_sum, off, 64);
        sim_sum += __shfl_down(sim_sum, off, 64);
    }
    if (lane == 0) {
        atomicAdd(&acc[(lvl * NCH + ch) * 2 + 0], sim_sum);
        atomicAdd(&acc[(lvl * NCH + ch) * 2 + 1], cs_sum);
    }
}

__global__ void finalize_k(const float* __restrict__ acc, float* __restrict__ out) {
    if (threadIdx.x != 0) return;
    const double w[5] = {0.0448, 0.2856, 0.3001, 0.2363, 0.1333};
    const double counts[5] = {1014.0 * 1014.0, 502.0 * 502.0, 246.0 * 246.0,
                              118.0 * 118.0, 54.0 * 54.0};
    double total = 0.0;
    for (int c = 0; c < NCH; ++c) {
        double pc = 1.0;
        for (int l = 0; l < 4; ++l) {
            double mcs = (double)acc[(l * NCH + c) * 2 + 1] / counts[l];
            pc *= pow(mcs, w[l]);
        }
        double ms4 = (double)acc[(4 * NCH + c) * 2 + 0] / counts[4];
        double p2 = pow(ms4, w[4]);
        pc *= (p2 * p2) * (p2 * p2);  // pow2[-1] appears in all 4 product terms
        total += pc;
    }
    *out = (float)(1.0 - total);
}

extern "C" void kernel_launch(void* const* d_in, const int* in_sizes, int n_in,
                              void* d_out, int out_size, void* d_ws, size_t ws_size,
                              hipStream_t stream) {
    const float* P0 = (const float*)d_in[0];
    const float* T0 = (const float*)d_in[1];
    float* out = (float*)d_out;
    float* acc = (float*)d_ws;  // 100 used, 128 reserved

    const size_t n1 = (size_t)NCH * 512 * 512;
    const size_t n2 = (size_t)NCH * 256 * 256;
    const size_t n3 = (size_t)NCH * 128 * 128;
    const size_t n4 = (size_t)NCH * 64 * 64;
    float* p1 = acc + 128;
    float* t1 = p1 + n1;
    float* p2 = t1 + n1;
    float* t2 = p2 + n2;
    float* p3 = t2 + n2;
    float* t3 = p3 + n3;
    float* p4 = t3 + n3;
    float* t4 = p4 + n4;

    pool_all<<<2560, 256, 0, stream>>>(P0, T0, p1, t1, p2, t2, p3, t3, p4, t4, acc);

    Ptrs ptrs;
    ptrs.p[0] = P0; ptrs.t[0] = T0;
    ptrs.p[1] = p1; ptrs.t[1] = t1;
    ptrs.p[2] = p2; ptrs.t[2] = t2;
    ptrs.p[3] = p3; ptrs.t[3] = t3;
    ptrs.p[4] = p4; ptrs.t[4] = t4;

    ssim_sw<<<dim3((NTASK + 3) / 4), 256, 0, stream>>>(ptrs, acc);

    finalize_k<<<1, 64, 0, stream>>>(acc, out);
}

// Round 6
// 211.247 us; speedup vs baseline: 1.2692x; 1.2692x over previous
//
#include <hip/hip_runtime.h>
#include <cstddef>

#define WIN 11
#define HALO 10
#define NCH 10

typedef float v4f __attribute__((ext_vector_type(4)));

// Normalized 1D Gaussian, sigma=1.5 (constexpr: unrolled taps fold to immediates)
constexpr float Gc[WIN] = {
    0.00102838f, 0.00759876f, 0.03600077f, 0.10936069f, 0.21300554f,
    0.26601173f, 0.21300554f, 0.10936069f, 0.03600077f, 0.00759876f,
    0.00102838f};

constexpr int HPITCH = 33;        // odd pitch: spread write banks
constexpr int RS = 76;            // ring slots; per-iter span 74 <= 76 (disjoint)
constexpr int RSZ = RS * HPITCH;  // 2508 v4f = 39.2 KB -> 4 blocks/CU
constexpr int NBLK = 174 * NCH;   // 1740 ssim blocks (finalize ticket target)

struct Ptrs {
    const float* p[5];
    const float* t[5];
};

// ---- One-shot pyramid: 64x64 lvl0 tile -> lvl1..4, plus acc zeroing ----
// (~110 MB in ~15us ~= 7 TB/s: at the HBM/L3 roofline — do not touch)
__global__ __launch_bounds__(256) void pool_all(
    const float* __restrict__ P0, const float* __restrict__ T0,
    float* __restrict__ p1, float* __restrict__ t1,
    float* __restrict__ p2, float* __restrict__ t2,
    float* __restrict__ p3, float* __restrict__ t3,
    float* __restrict__ p4, float* __restrict__ t4,
    float* __restrict__ acc) {
    __shared__ float sp2[256], st2[256], sp3[64], st3[64];
    const int tid = threadIdx.x;
    if (blockIdx.x == 0 && tid < 128) acc[tid] = 0.f;  // sums + ticket zeroed

    const int b = blockIdx.x;  // 2560 = 10ch x 16 x 16
    const int bx = b & 15, by = (b >> 4) & 15, ch = b >> 8;
    const int tx = tid & 15, ty = tid >> 4;

    const size_t rbase =
        ((size_t)ch * 1024 + by * 64 + ty * 4) * 1024 + bx * 64 + tx * 4;
    float4 pr[4], tr[4];
#pragma unroll
    for (int r2 = 0; r2 < 4; ++r2) {
        pr[r2] = *(const float4*)(P0 + rbase + (size_t)r2 * 1024);
        tr[r2] = *(const float4*)(T0 + rbase + (size_t)r2 * 1024);
    }
    float p1a = 0.25f * ((pr[0].x + pr[0].y) + (pr[1].x + pr[1].y));
    float p1b = 0.25f * ((pr[0].z + pr[0].w) + (pr[1].z + pr[1].w));
    float p1c = 0.25f * ((pr[2].x + pr[2].y) + (pr[3].x + pr[3].y));
    float p1d = 0.25f * ((pr[2].z + pr[2].w) + (pr[3].z + pr[3].w));
    float t1a = 0.25f * ((tr[0].x + tr[0].y) + (tr[1].x + tr[1].y));
    float t1b = 0.25f * ((tr[0].z + tr[0].w) + (tr[1].z + tr[1].w));
    float t1c = 0.25f * ((tr[2].x + tr[2].y) + (tr[3].x + tr[3].y));
    float t1d = 0.25f * ((tr[2].z + tr[2].w) + (tr[3].z + tr[3].w));
    size_t o1 = ((size_t)ch * 512 + by * 32 + ty * 2) * 512 + bx * 32 + tx * 2;
    *(float2*)(p1 + o1) = make_float2(p1a, p1b);
    *(float2*)(p1 + o1 + 512) = make_float2(p1c, p1d);
    *(float2*)(t1 + o1) = make_float2(t1a, t1b);
    *(float2*)(t1 + o1 + 512) = make_float2(t1c, t1d);
    float p2v = 0.25f * ((p1a + p1b) + (p1c + p1d));
    float t2v = 0.25f * ((t1a + t1b) + (t1c + t1d));
    size_t o2 = ((size_t)ch * 256 + by * 16 + ty) * 256 + bx * 16 + tx;
    p2[o2] = p2v;
    t2[o2] = t2v;
    sp2[tid] = p2v;
    st2[tid] = t2v;
    __syncthreads();
    if (tid < 64) {
        int x3 = tid & 7, y3 = tid >> 3;
        int i0 = (2 * y3) * 16 + 2 * x3;
        float p3v = 0.25f * ((sp2[i0] + sp2[i0 + 1]) + (sp2[i0 + 16] + sp2[i0 + 17]));
        float t3v = 0.25f * ((st2[i0] + st2[i0 + 1]) + (st2[i0 + 16] + st2[i0 + 17]));
        size_t o3 = ((size_t)ch * 128 + by * 8 + y3) * 128 + bx * 8 + x3;
        p3[o3] = p3v;
        t3[o3] = t3v;
        sp3[tid] = p3v;
        st3[tid] = t3v;
    }
    __syncthreads();
    if (tid < 16) {
        int x4 = tid & 3, y4 = tid >> 2;
        int i0 = (2 * y4) * 8 + 2 * x4;
        float p4v = 0.25f * ((sp3[i0] + sp3[i0 + 1]) + (sp3[i0 + 8] + sp3[i0 + 9]));
        float t4v = 0.25f * ((st3[i0] + st3[i0 + 1]) + (st3[i0 + 8] + st3[i0 + 9]));
        size_t o4 = ((size_t)ch * 64 + by * 4 + y4) * 64 + bx * 4 + x4;
        p4[o4] = p4v;
        t4[o4] = t4v;
    }
}

// Column-strip streaming SSIM, 4-channel ring (p, t, p^2+t^2, p*t).
// Structure = R0 (proven 88us) EXCEPT:
//  (1) main-loop barrier is lgkmcnt(0)-only + raw s_barrier: LDS writes are
//      made visible, but producer global loads (batch i+1, issued pre-barrier)
//      stay IN FLIGHT across it — __syncthreads' vmcnt(0) drain was forcing
//      full HBM latency onto every iteration's critical path (m97 stall).
//      Register deps stay scoreboard-safe (compiler emits vmcnt(N) before the
//      conv_store8 use); sched_barrier(0) pins DS ops after the barrier.
//  (2) emit uses v_rcp_f32 (proven absmax 0.0 in R4's run).
//  (3) finalize fused: last block (device ticket) computes the output.
__global__ __launch_bounds__(256) void ssim_strip(Ptrs ptrs,
                                                  float* __restrict__ acc,
                                                  float* __restrict__ out) {
    __shared__ v4f hq[RSZ];  // 40128 B -> 4 blocks/CU
    __shared__ float red[8];
    __shared__ double dred[10];
    __shared__ int isLast;

    const int bxi = blockIdx.x;  // 0..173
    int lvl, base;
    if (bxi < 128)      { lvl = 0; base = 0; }
    else if (bxi < 160) { lvl = 1; base = 128; }
    else if (bxi < 168) { lvl = 2; base = 160; }
    else if (bxi < 172) { lvl = 3; base = 168; }
    else                { lvl = 4; base = 172; }
    const int local = bxi - base;
    const int H = 1024 >> lvl;
    const int Wout = H - HALO;
    const int ncol = 32 >> lvl;
    const int cs = local & (ncol - 1);
    const int rsi = local >> (5 - lvl);
    const int X0 = cs * 32;
    const int strip_y0 = rsi * 256;
    const int strip_rows = min(256, Wout - strip_y0);
    const int rows_needed = strip_rows + HALO;
    const int nIter = (strip_rows + 31) >> 5;

    const int c = blockIdx.y;
    const float* Pc = ptrs.p[lvl] + (size_t)c * H * H;
    const float* Tc = ptrs.t[lvl] + (size_t)c * H * H;
    const int tid = threadIdx.x;

    // load 18 cols (9 float2) of row gy at col base gxb
    auto load_row18 = [&](int gy, int gxb, float2 lp[9], float2 lt[9]) {
        const float* Pr = Pc + (size_t)gy * H + gxb;
        const float* Tr = Tc + (size_t)gy * H + gxb;
        if (gxb + 18 <= H) {
#pragma unroll
            for (int j = 0; j < 9; ++j) {
                lp[j] = *(const float2*)(Pr + 2 * j);
                lt[j] = *(const float2*)(Tr + 2 * j);
            }
        } else {
#pragma unroll
            for (int j = 0; j < 9; ++j) {
                float2 a = make_float2(0.f, 0.f), b = make_float2(0.f, 0.f);
                if (gxb + 2 * j < H)     { a.x = Pr[2 * j];     b.x = Tr[2 * j]; }
                if (gxb + 2 * j + 1 < H) { a.y = Pr[2 * j + 1]; b.y = Tr[2 * j + 1]; }
                lp[j] = a;
                lt[j] = b;
            }
        }
    };

    // horizontal conv: 8 outputs (cols x0..x0+7) from 18 inputs -> ring slot rr
    auto conv_store8 = [&](int rr, int x0, const float2 lp[9], const float2 lt[9]) {
        v4f aq[8] = {};
#pragma unroll
        for (int xi = 0; xi < 18; ++xi) {
            float pv = (xi & 1) ? lp[xi >> 1].y : lp[xi >> 1].x;
            float tv = (xi & 1) ? lt[xi >> 1].y : lt[xi >> 1].x;
            v4f xq = (v4f){pv, tv, pv * pv + tv * tv, pv * tv};
#pragma unroll
            for (int o = 0; o < 8; ++o) {
                int k = xi - o;
                if (k >= 0 && k <= 10) aq[o] = aq[o] + Gc[k] * xq;  // 2x pk_fma
            }
        }
        const int sb = rr * HPITCH + x0;
#pragma unroll
        for (int o = 0; o < 8; ++o) hq[sb + o] = aq[o];  // ds_write_b128
    };

    // ---- Prologue: h-rows 0..41 via 42 rows x 4 segs (168 threads) ----
    {
        const int r = tid >> 2, seg = tid & 3;
        if (r < 42) {
            float2 lp[9], lt[9];
            load_row18(strip_y0 + r, X0 + 8 * seg, lp, lt);
            conv_store8(r, 8 * seg, lp, lt);
        }
    }

    // ---- Producer preload of batch 0 (rows 42..73) ----
    const bool isProd = (tid >= 128);
    const int pr = tid & 31;          // producer row in batch
    const int pseg = (tid >> 5) & 3;  // producer 8-col segment
    float2 plp[9], plt[9];
    int prRow = 42 + pr;              // absolute h-row of current loaded batch
    int prSlot = prRow;               // ring slot (42+pr < 76)
    bool pHave = false;
    if (isProd && prRow < rows_needed && nIter > 1) {
        load_row18(strip_y0 + prRow, X0 + 8 * pseg, plp, plt);
        pHave = true;
    }
    __syncthreads();

    // ---- Main loop: 32 output rows/iter, 1 barrier/iter ----
    float cs_sum = 0.f, sim_sum = 0.f;
    const int txl = tid & 31;
    const int g = (tid >> 5) & 3;  // consumer band (tid<128): rows 8g..8g+7
    int y0m = 0;                   // (32*i) % RS
    for (int i = 0; i < nIter; ++i) {
        if (isProd) {
            // store batch i (loaded last iter), then issue batch i+1 loads
            if (pHave) conv_store8(prSlot, 8 * pseg, plp, plt);
            prSlot += 32;
            if (prSlot >= RS) prSlot -= RS;
            prRow += 32;
            pHave = (prRow < rows_needed) && (i + 2 < nIter + 1) && (i + 1 < nIter);
            if (pHave) load_row18(strip_y0 + prRow, X0 + 8 * pseg, plp, plt);
        } else {
            // S2: 8 outputs over 18 resident ring rows
            int sl = y0m + 8 * g;
            if (sl >= RS) sl -= RS;
            v4f a[8] = {};
#pragma unroll
            for (int yr = 0; yr < 18; ++yr) {
                v4f vq = hq[sl * HPITCH + txl];  // ds_read_b128
#pragma unroll
                for (int o = 0; o < 8; ++o) {
                    int k = yr - o;
                    if (k >= 0 && k <= 10) a[o] = a[o] + Gc[k] * vq;  // 2x pk_fma
                }
                ++sl;
                if (sl >= RS) sl = 0;
            }
            const float C1c = 1.0e-4f, C2c = 9.0e-4f;
            const bool colok = (X0 + txl) < Wout;
            const int orow0 = 32 * i + 8 * g;
#pragma unroll
            for (int o = 0; o < 8; ++o) {
                if (colok && (orow0 + o) < strip_rows) {
                    float mu1 = a[o].x, mu2 = a[o].y;
                    float mu1s = mu1 * mu1, mu2s = mu2 * mu2, mu12 = mu1 * mu2;
                    float v2 = a[o].z - mu1s - mu2s + C2c;
                    float v1 = 2.f * (a[o].w - mu12) + C2c;
                    float den2 = mu1s + mu2s + C1c;
                    float num2 = 2.f * mu12 + C1c;
                    // v_rcp_f32 (<=1 ulp, absmax held 0.0 in R4's passing run)
                    float inv = __builtin_amdgcn_rcpf(v2 * den2);
                    cs_sum = fmaf(v1 * den2, inv, cs_sum);
                    sim_sum = fmaf(num2 * v1, inv, sim_sum);
                }
            }
        }
        y0m += 32;
        if (y0m >= RS) y0m -= RS;
        // Relaxed barrier: drain LDS (writes visible to next iter's readers)
        // but NOT vmcnt — producer prefetch loads stay in flight across it.
        asm volatile("s_waitcnt lgkmcnt(0)" ::: "memory");
        __builtin_amdgcn_s_barrier();
        __builtin_amdgcn_sched_barrier(0);
    }

    // ---- Block reduction (producers contribute zeros) ----
#pragma unroll
    for (int off = 32; off > 0; off >>= 1) {
        cs_sum += __shfl_down(cs_sum, off, 64);
        sim_sum += __shfl_down(sim_sum, off, 64);
    }
    int wave = tid >> 6;
    if ((tid & 63) == 0) {
        red[wave * 2 + 0] = sim_sum;
        red[wave * 2 + 1] = cs_sum;
    }
    __syncthreads();
    if (tid == 0) {
        float s = red[0] + red[2] + red[4] + red[6];
        float cc = red[1] + red[3] + red[5] + red[7];
        atomicAdd(&acc[(lvl * NCH + c) * 2 + 0], s);
        atomicAdd(&acc[(lvl * NCH + c) * 2 + 1], cc);
        __threadfence();  // release: sums visible before ticket
        unsigned t = atomicAdd((unsigned int*)acc + 112, 1u);
        isLast = (t == (unsigned)(NBLK - 1));
    }
    __syncthreads();

    // ---- Fused finalize: last block computes the scalar output ----
    if (isLast) {
        __threadfence();  // acquire side
        if (tid < 10) {   // one lane per channel (all in wave 0)
            const double w[5] = {0.0448, 0.2856, 0.3001, 0.2363, 0.1333};
            const double counts[5] = {1014.0 * 1014.0, 502.0 * 502.0,
                                      246.0 * 246.0, 118.0 * 118.0, 54.0 * 54.0};
            double pc = 1.0;
            for (int l = 0; l < 4; ++l) {
                // device-scope read of atomically-written sums
                float v = atomicAdd(&acc[(l * NCH + tid) * 2 + 1], 0.0f);
                pc *= pow((double)v / counts[l], w[l]);
            }
            float s4 = atomicAdd(&acc[(4 * NCH + tid) * 2 + 0], 0.0f);
            double p2 = pow((double)s4 / counts[4], w[4]);
            pc *= (p2 * p2) * (p2 * p2);  // pow2[-1] in all 4 product terms
            dred[tid] = pc;
        }
        if (tid == 0) {
            double total = 0.0;
            for (int k = 0; k < 10; ++k) total += dred[k];
            *out = (float)(1.0 - total);
        }
    }
}

extern "C" void kernel_launch(void* const* d_in, const int* in_sizes, int n_in,
                              void* d_out, int out_size, void* d_ws, size_t ws_size,
                              hipStream_t stream) {
    const float* P0 = (const float*)d_in[0];
    const float* T0 = (const float*)d_in[1];
    float* out = (float*)d_out;
    float* acc = (float*)d_ws;  // 100 sums + ticket@uint112, 128 reserved

    const size_t n1 = (size_t)NCH * 512 * 512;
    const size_t n2 = (size_t)NCH * 256 * 256;
    const size_t n3 = (size_t)NCH * 128 * 128;
    const size_t n4 = (size_t)NCH * 64 * 64;
    float* p1 = acc + 128;
    float* t1 = p1 + n1;
    float* p2 = t1 + n1;
    float* t2 = p2 + n2;
    float* p3 = t2 + n2;
    float* t3 = p3 + n3;
    float* p4 = t3 + n3;
    float* t4 = p4 + n4;

    pool_all<<<2560, 256, 0, stream>>>(P0, T0, p1, t1, p2, t2, p3, t3, p4, t4, acc);

    Ptrs ptrs;
    ptrs.p[0] = P0; ptrs.t[0] = T0;
    ptrs.p[1] = p1; ptrs.t[1] = t1;
    ptrs.p[2] = p2; ptrs.t[2] = t2;
    ptrs.p[3] = p3; ptrs.t[3] = t3;
    ptrs.p[4] = p4; ptrs.t[4] = t4;

    ssim_strip<<<dim3(174, NCH, 1), 256, 0, stream>>>(ptrs, acc, out);
}

// Round 7
// 211.142 us; speedup vs baseline: 1.2698x; 1.0005x over previous
//
#include <hip/hip_runtime.h>
#include <cstddef>

#define WIN 11
#define HALO 10
#define NCH 10

typedef float v4f __attribute__((ext_vector_type(4)));

// Normalized 1D Gaussian, sigma=1.5 (constexpr: unrolled taps fold to immediates)
constexpr float Gc[WIN] = {
    0.00102838f, 0.00759876f, 0.03600077f, 0.10936069f, 0.21300554f,
    0.26601173f, 0.21300554f, 0.10936069f, 0.03600077f, 0.00759876f,
    0.00102838f};

constexpr int HPITCH = 33;        // odd pitch: spread write banks
constexpr int RS = 76;            // ring slots; per-iter span 74 <= 76 (disjoint)
constexpr int RSZ = RS * HPITCH;  // 2508 v4f = 39.2 KB -> 4 blocks/CU
constexpr int NBLK = 174 * NCH;   // 1740 ssim blocks (finalize ticket target)

struct Ptrs {
    const float* p[5];
    const float* t[5];
};

// ---- One-shot pyramid: 64x64 lvl0 tile -> lvl1..4, plus acc zeroing ----
// (~110 MB in ~15us ~= 7 TB/s: at the HBM/L3 roofline — do not touch)
__global__ __launch_bounds__(256) void pool_all(
    const float* __restrict__ P0, const float* __restrict__ T0,
    float* __restrict__ p1, float* __restrict__ t1,
    float* __restrict__ p2, float* __restrict__ t2,
    float* __restrict__ p3, float* __restrict__ t3,
    float* __restrict__ p4, float* __restrict__ t4,
    float* __restrict__ acc) {
    __shared__ float sp2[256], st2[256], sp3[64], st3[64];
    const int tid = threadIdx.x;
    if (blockIdx.x == 0 && tid < 128) acc[tid] = 0.f;  // sums + ticket zeroed

    const int b = blockIdx.x;  // 2560 = 10ch x 16 x 16
    const int bx = b & 15, by = (b >> 4) & 15, ch = b >> 8;
    const int tx = tid & 15, ty = tid >> 4;

    const size_t rbase =
        ((size_t)ch * 1024 + by * 64 + ty * 4) * 1024 + bx * 64 + tx * 4;
    float4 pr[4], tr[4];
#pragma unroll
    for (int r2 = 0; r2 < 4; ++r2) {
        pr[r2] = *(const float4*)(P0 + rbase + (size_t)r2 * 1024);
        tr[r2] = *(const float4*)(T0 + rbase + (size_t)r2 * 1024);
    }
    float p1a = 0.25f * ((pr[0].x + pr[0].y) + (pr[1].x + pr[1].y));
    float p1b = 0.25f * ((pr[0].z + pr[0].w) + (pr[1].z + pr[1].w));
    float p1c = 0.25f * ((pr[2].x + pr[2].y) + (pr[3].x + pr[3].y));
    float p1d = 0.25f * ((pr[2].z + pr[2].w) + (pr[3].z + pr[3].w));
    float t1a = 0.25f * ((tr[0].x + tr[0].y) + (tr[1].x + tr[1].y));
    float t1b = 0.25f * ((tr[0].z + tr[0].w) + (tr[1].z + tr[1].w));
    float t1c = 0.25f * ((tr[2].x + tr[2].y) + (tr[3].x + tr[3].y));
    float t1d = 0.25f * ((tr[2].z + tr[2].w) + (tr[3].z + tr[3].w));
    size_t o1 = ((size_t)ch * 512 + by * 32 + ty * 2) * 512 + bx * 32 + tx * 2;
    *(float2*)(p1 + o1) = make_float2(p1a, p1b);
    *(float2*)(p1 + o1 + 512) = make_float2(p1c, p1d);
    *(float2*)(t1 + o1) = make_float2(t1a, t1b);
    *(float2*)(t1 + o1 + 512) = make_float2(t1c, t1d);
    float p2v = 0.25f * ((p1a + p1b) + (p1c + p1d));
    float t2v = 0.25f * ((t1a + t1b) + (t1c + t1d));
    size_t o2 = ((size_t)ch * 256 + by * 16 + ty) * 256 + bx * 16 + tx;
    p2[o2] = p2v;
    t2[o2] = t2v;
    sp2[tid] = p2v;
    st2[tid] = t2v;
    __syncthreads();
    if (tid < 64) {
        int x3 = tid & 7, y3 = tid >> 3;
        int i0 = (2 * y3) * 16 + 2 * x3;
        float p3v = 0.25f * ((sp2[i0] + sp2[i0 + 1]) + (sp2[i0 + 16] + sp2[i0 + 17]));
        float t3v = 0.25f * ((st2[i0] + st2[i0 + 1]) + (st2[i0 + 16] + st2[i0 + 17]));
        size_t o3 = ((size_t)ch * 128 + by * 8 + y3) * 128 + bx * 8 + x3;
        p3[o3] = p3v;
        t3[o3] = t3v;
        sp3[tid] = p3v;
        st3[tid] = t3v;
    }
    __syncthreads();
    if (tid < 16) {
        int x4 = tid & 3, y4 = tid >> 2;
        int i0 = (2 * y4) * 8 + 2 * x4;
        float p4v = 0.25f * ((sp3[i0] + sp3[i0 + 1]) + (sp3[i0 + 8] + sp3[i0 + 9]));
        float t4v = 0.25f * ((st3[i0] + st3[i0 + 1]) + (st3[i0 + 8] + st3[i0 + 9]));
        size_t o4 = ((size_t)ch * 64 + by * 4 + y4) * 64 + bx * 4 + x4;
        p4[o4] = p4v;
        t4[o4] = t4v;
    }
}

// Column-strip streaming SSIM, 4-channel ring (p, t, p^2+t^2, p*t).
// Structure = R0's proven 88us schedule (plain __syncthreads in the loop —
// R6's lgkmcnt-only barrier + sched_barrier(0) pinned the schedule and LOST
// 45us, the m141 failure mode; the compiler's own cross-barrier scheduling is
// near-optimal here). Deltas vs R0, both individually proven (absmax 0.0):
//  (1) emit uses v_rcp_f32 (<=1 ulp).
//  (2) finalize fused: last block (device ticket) computes the output,
//      saving the finalize_k dispatch + its serial 50x double-pow (~35us).
__global__ __launch_bounds__(256) void ssim_strip(Ptrs ptrs,
                                                  float* __restrict__ acc,
                                                  float* __restrict__ out) {
    __shared__ v4f hq[RSZ];  // 40128 B -> 4 blocks/CU
    __shared__ float red[8];
    __shared__ double dred[10];
    __shared__ int isLast;

    const int bxi = blockIdx.x;  // 0..173
    int lvl, base;
    if (bxi < 128)      { lvl = 0; base = 0; }
    else if (bxi < 160) { lvl = 1; base = 128; }
    else if (bxi < 168) { lvl = 2; base = 160; }
    else if (bxi < 172) { lvl = 3; base = 168; }
    else                { lvl = 4; base = 172; }
    const int local = bxi - base;
    const int H = 1024 >> lvl;
    const int Wout = H - HALO;
    const int ncol = 32 >> lvl;
    const int cs = local & (ncol - 1);
    const int rsi = local >> (5 - lvl);
    const int X0 = cs * 32;
    const int strip_y0 = rsi * 256;
    const int strip_rows = min(256, Wout - strip_y0);
    const int rows_needed = strip_rows + HALO;
    const int nIter = (strip_rows + 31) >> 5;

    const int c = blockIdx.y;
    const float* Pc = ptrs.p[lvl] + (size_t)c * H * H;
    const float* Tc = ptrs.t[lvl] + (size_t)c * H * H;
    const int tid = threadIdx.x;

    // load 18 cols (9 float2) of row gy at col base gxb
    auto load_row18 = [&](int gy, int gxb, float2 lp[9], float2 lt[9]) {
        const float* Pr = Pc + (size_t)gy * H + gxb;
        const float* Tr = Tc + (size_t)gy * H + gxb;
        if (gxb + 18 <= H) {
#pragma unroll
            for (int j = 0; j < 9; ++j) {
                lp[j] = *(const float2*)(Pr + 2 * j);
                lt[j] = *(const float2*)(Tr + 2 * j);
            }
        } else {
#pragma unroll
            for (int j = 0; j < 9; ++j) {
                float2 a = make_float2(0.f, 0.f), b = make_float2(0.f, 0.f);
                if (gxb + 2 * j < H)     { a.x = Pr[2 * j];     b.x = Tr[2 * j]; }
                if (gxb + 2 * j + 1 < H) { a.y = Pr[2 * j + 1]; b.y = Tr[2 * j + 1]; }
                lp[j] = a;
                lt[j] = b;
            }
        }
    };

    // horizontal conv: 8 outputs (cols x0..x0+7) from 18 inputs -> ring slot rr
    auto conv_store8 = [&](int rr, int x0, const float2 lp[9], const float2 lt[9]) {
        v4f aq[8] = {};
#pragma unroll
        for (int xi = 0; xi < 18; ++xi) {
            float pv = (xi & 1) ? lp[xi >> 1].y : lp[xi >> 1].x;
            float tv = (xi & 1) ? lt[xi >> 1].y : lt[xi >> 1].x;
            v4f xq = (v4f){pv, tv, pv * pv + tv * tv, pv * tv};
#pragma unroll
            for (int o = 0; o < 8; ++o) {
                int k = xi - o;
                if (k >= 0 && k <= 10) aq[o] = aq[o] + Gc[k] * xq;  // 2x pk_fma
            }
        }
        const int sb = rr * HPITCH + x0;
#pragma unroll
        for (int o = 0; o < 8; ++o) hq[sb + o] = aq[o];  // ds_write_b128
    };

    // ---- Prologue: h-rows 0..41 via 42 rows x 4 segs (168 threads) ----
    {
        const int r = tid >> 2, seg = tid & 3;
        if (r < 42) {
            float2 lp[9], lt[9];
            load_row18(strip_y0 + r, X0 + 8 * seg, lp, lt);
            conv_store8(r, 8 * seg, lp, lt);
        }
    }

    // ---- Producer preload of batch 0 (rows 42..73) ----
    const bool isProd = (tid >= 128);
    const int pr = tid & 31;          // producer row in batch
    const int pseg = (tid >> 5) & 3;  // producer 8-col segment
    float2 plp[9], plt[9];
    int prRow = 42 + pr;              // absolute h-row of current loaded batch
    int prSlot = prRow;               // ring slot (42+pr < 76)
    bool pHave = false;
    if (isProd && prRow < rows_needed && nIter > 1) {
        load_row18(strip_y0 + prRow, X0 + 8 * pseg, plp, plt);
        pHave = true;
    }
    __syncthreads();

    // ---- Main loop: 32 output rows/iter, 1 barrier/iter ----
    float cs_sum = 0.f, sim_sum = 0.f;
    const int txl = tid & 31;
    const int g = (tid >> 5) & 3;  // consumer band (tid<128): rows 8g..8g+7
    int y0m = 0;                   // (32*i) % RS
    for (int i = 0; i < nIter; ++i) {
        if (isProd) {
            // store batch i (loaded last iter), then issue batch i+1 loads
            if (pHave) conv_store8(prSlot, 8 * pseg, plp, plt);
            prSlot += 32;
            if (prSlot >= RS) prSlot -= RS;
            prRow += 32;
            pHave = (prRow < rows_needed) && (i + 2 < nIter + 1) && (i + 1 < nIter);
            if (pHave) load_row18(strip_y0 + prRow, X0 + 8 * pseg, plp, plt);
        } else {
            // S2: 8 outputs over 18 resident ring rows
            int sl = y0m + 8 * g;
            if (sl >= RS) sl -= RS;
            v4f a[8] = {};
#pragma unroll
            for (int yr = 0; yr < 18; ++yr) {
                v4f vq = hq[sl * HPITCH + txl];  // ds_read_b128
#pragma unroll
                for (int o = 0; o < 8; ++o) {
                    int k = yr - o;
                    if (k >= 0 && k <= 10) a[o] = a[o] + Gc[k] * vq;  // 2x pk_fma
                }
                ++sl;
                if (sl >= RS) sl = 0;
            }
            const float C1c = 1.0e-4f, C2c = 9.0e-4f;
            const bool colok = (X0 + txl) < Wout;
            const int orow0 = 32 * i + 8 * g;
#pragma unroll
            for (int o = 0; o < 8; ++o) {
                if (colok && (orow0 + o) < strip_rows) {
                    float mu1 = a[o].x, mu2 = a[o].y;
                    float mu1s = mu1 * mu1, mu2s = mu2 * mu2, mu12 = mu1 * mu2;
                    float v2 = a[o].z - mu1s - mu2s + C2c;
                    float v1 = 2.f * (a[o].w - mu12) + C2c;
                    float den2 = mu1s + mu2s + C1c;
                    float num2 = 2.f * mu12 + C1c;
                    // v_rcp_f32 (<=1 ulp, absmax held 0.0 in R4/R6 runs)
                    float inv = __builtin_amdgcn_rcpf(v2 * den2);
                    cs_sum = fmaf(v1 * den2, inv, cs_sum);
                    sim_sum = fmaf(num2 * v1, inv, sim_sum);
                }
            }
        }
        y0m += 32;
        if (y0m >= RS) y0m -= RS;
        __syncthreads();
    }

    // ---- Block reduction (producers contribute zeros) ----
#pragma unroll
    for (int off = 32; off > 0; off >>= 1) {
        cs_sum += __shfl_down(cs_sum, off, 64);
        sim_sum += __shfl_down(sim_sum, off, 64);
    }
    int wave = tid >> 6;
    if ((tid & 63) == 0) {
        red[wave * 2 + 0] = sim_sum;
        red[wave * 2 + 1] = cs_sum;
    }
    __syncthreads();
    if (tid == 0) {
        float s = red[0] + red[2] + red[4] + red[6];
        float cc = red[1] + red[3] + red[5] + red[7];
        atomicAdd(&acc[(lvl * NCH + c) * 2 + 0], s);
        atomicAdd(&acc[(lvl * NCH + c) * 2 + 1], cc);
        __threadfence();  // release: sums visible before ticket
        unsigned t = atomicAdd((unsigned int*)acc + 112, 1u);
        isLast = (t == (unsigned)(NBLK - 1));
    }
    __syncthreads();

    // ---- Fused finalize: last block computes the scalar output ----
    if (isLast) {
        __threadfence();  // acquire side
        if (tid < 10) {   // one lane per channel (all in wave 0)
            const double w[5] = {0.0448, 0.2856, 0.3001, 0.2363, 0.1333};
            const double counts[5] = {1014.0 * 1014.0, 502.0 * 502.0,
                                      246.0 * 246.0, 118.0 * 118.0, 54.0 * 54.0};
            double pc = 1.0;
            for (int l = 0; l < 4; ++l) {
                // device-scope read of atomically-written sums
                float v = atomicAdd(&acc[(l * NCH + tid) * 2 + 1], 0.0f);
                pc *= pow((double)v / counts[l], w[l]);
            }
            float s4 = atomicAdd(&acc[(4 * NCH + tid) * 2 + 0], 0.0f);
            double p2 = pow((double)s4 / counts[4], w[4]);
            pc *= (p2 * p2) * (p2 * p2);  // pow2[-1] in all 4 product terms
            dred[tid] = pc;
        }
        if (tid == 0) {
            double total = 0.0;
            for (int k = 0; k < 10; ++k) total += dred[k];
            *out = (float)(1.0 - total);
        }
    }
}

extern "C" void kernel_launch(void* const* d_in, const int* in_sizes, int n_in,
                              void* d_out, int out_size, void* d_ws, size_t ws_size,
                              hipStream_t stream) {
    const float* P0 = (const float*)d_in[0];
    const float* T0 = (const float*)d_in[1];
    float* out = (float*)d_out;
    float* acc = (float*)d_ws;  // 100 sums + ticket@uint112, 128 reserved

    const size_t n1 = (size_t)NCH * 512 * 512;
    const size_t n2 = (size_t)NCH * 256 * 256;
    const size_t n3 = (size_t)NCH * 128 * 128;
    const size_t n4 = (size_t)NCH * 64 * 64;
    float* p1 = acc + 128;
    float* t1 = p1 + n1;
    float* p2 = t1 + n1;
    float* t2 = p2 + n2;
    float* p3 = t2 + n2;
    float* t3 = p3 + n3;
    float* p4 = t3 + n3;
    float* t4 = p4 + n4;

    pool_all<<<2560, 256, 0, stream>>>(P0, T0, p1, t1, p2, t2, p3, t3, p4, t4, acc);

    Ptrs ptrs;
    ptrs.p[0] = P0; ptrs.t[0] = T0;
    ptrs.p[1] = p1; ptrs.t[1] = t1;
    ptrs.p[2] = p2; ptrs.t[2] = t2;
    ptrs.p[3] = p3; ptrs.t[3] = t3;
    ptrs.p[4] = p4; ptrs.t[4] = t4;

    ssim_strip<<<dim3(174, NCH, 1), 256, 0, stream>>>(ptrs, acc, out);
}